// Round 22
// baseline (74.872 us; speedup 1.0000x reference)
//
#include <hip/hip_runtime.h>
#include <math.h>

// Sizes fixed by the reference.
#define BSZ  16
#define DIM  1024
#define SB   (BSZ * DIM)   // 16384 floats between consecutive s-rows

__device__ __forceinline__ float sigmoidf_(float v) {
    return __builtin_amdgcn_rcpf(1.0f + __expf(-v));
}

// R22 — DECOMPOSITION CHANGE. Seven scheduling/granule theories all null:
// every LDS-staged variant pins at ~3.3-3.4 TB/s because each block touches
// a 64-128B d-sliver of every 64KB s-row (machine never streams contiguous
// memory; fillBuffer's contiguous sweep hits 6.7 TB/s on this chip).
// New mapping: lane = one (b,d) channel, s serial per lane.
//   - 256 blocks x 64 lanes = all 16*1024 (b,d) units; block = 64 consecutive
//     d of one b -> every wave load/store is 256B CONTIGUOUS, and the 256
//     blocks in s-lockstep collectively cover each 64KB s-row completely ->
//     machine-level streaming (the fill pattern).
//   - recurrence row-major per lane: prev-row state H/V[32] in REGISTERS
//     (statically indexed: j fully unrolled), left-neighbor state in scalars.
//     No LDS, no barriers, no cross-lane ops.
//   - row-ahead prefetch XA/XB (i unrolled x2): issue-to-use = 32 cells
//     (~1500cy) >> HBM latency; guard row-32 OOB with uniform branch.
//   v[i,j] = a2*h[i-1,j] + a1*v[i-1,j] + b2*x   (prev row, own lane)
//   h[i,j] = a1*h[i,j-1] + a2*v[i,j-1] + b1*x   (prev col, scalars)
//   out = silu(<h,C1s>+<v,C2s> + x*om)
__global__ __launch_bounds__(64, 1) void ssm2d_kernel(
    const float* __restrict__ x,
    const float* __restrict__ A1, const float* __restrict__ A2,
    const float* __restrict__ B1, const float* __restrict__ B2,
    const float* __restrict__ C1, const float* __restrict__ C2,
    const float* __restrict__ omega,
    float* __restrict__ out)
{
    // XCD-contiguity: XCD x owns d in [x*128, x*128+128) for every b.
    const int lx   = blockIdx.x;          // 0..255
    const int xcd  = lx & 7;
    const int hi   = (lx >> 3) & 1;
    const int b    = lx >> 4;             // 0..15
    const int d0   = (xcd * 2 + hi) * 64; // 0..960, step 64
    const int lane = threadIdx.x;         // 0..63
    const int d    = d0 + lane;

    // ---- per-lane coefficients ----
    const float2 fA1 = *reinterpret_cast<const float2*>(A1 + 2 * d);
    const float2 fA2 = *reinterpret_cast<const float2*>(A2 + 2 * d);
    const float2 fB1 = *reinterpret_cast<const float2*>(B1 + 2 * d);
    const float2 fB2 = *reinterpret_cast<const float2*>(B2 + 2 * d);
    const float2 fC1 = *reinterpret_cast<const float2*>(C1 + 2 * d);
    const float2 fC2 = *reinterpret_cast<const float2*>(C2 + 2 * d);
    const float  om  = omega[d];

    const float a1c0 = sigmoidf_(fA1.x) * 0.5f, a1c1 = sigmoidf_(fA1.y) * 0.5f;
    const float a2c0 = sigmoidf_(fA2.x) * 0.5f, a2c1 = sigmoidf_(fA2.y) * 0.5f;
    const float b1c0 = sigmoidf_(fB1.x) * 0.5f, b1c1 = sigmoidf_(fB1.y) * 0.5f;
    const float b2c0 = sigmoidf_(fB2.x) * 0.5f, b2c1 = sigmoidf_(fB2.y) * 0.5f;
    const float sc   = 0.70710678118654752f;
    const float c1s0 = fC1.x * sc, c1s1 = fC1.y * sc;
    const float c2s0 = fC2.x * sc, c2s1 = fC2.y * sc;

    const float* xp = x   + (size_t)b * DIM + d;
    float*       op = out + (size_t)b * DIM + d;

    // ---- prev-row state in registers (statically indexed) ----
    float H0[32], H1[32], V0[32], V1[32];
    #pragma unroll
    for (int j = 0; j < 32; ++j) { H0[j] = 0.f; H1[j] = 0.f; V0[j] = 0.f; V1[j] = 0.f; }

    // ---- row prefetch buffers ----
    float XA[32], XB[32];
    #pragma unroll
    for (int j = 0; j < 32; ++j) XA[j] = xp[(size_t)j * SB];   // row 0

#define CELL(ROW, J, XV) do {                                                \
        const float xv  = (XV);                                              \
        const float vn0 = fmaf(a2c0, H0[J], fmaf(a1c0, V0[J], b2c0 * xv));   \
        const float vn1 = fmaf(a2c1, H1[J], fmaf(a1c1, V1[J], b2c1 * xv));   \
        const float hn0 = fmaf(a1c0, hL0, fmaf(a2c0, vL0, b1c0 * xv));       \
        const float hn1 = fmaf(a1c1, hL1, fmaf(a2c1, vL1, b1c1 * xv));       \
        float y = hn0 * c1s0;                                                \
        y = fmaf(hn1, c1s1, y);                                              \
        y = fmaf(vn0, c2s0, y);                                              \
        y = fmaf(vn1, c2s1, y);                                              \
        const float z = fmaf(xv, om, y);                                     \
        op[(size_t)((ROW) * 32 + (J)) * SB] = z * sigmoidf_(z);              \
        H0[J] = hn0; H1[J] = hn1; V0[J] = vn0; V1[J] = vn1;                  \
        hL0 = hn0; hL1 = hn1; vL0 = vn0; vL1 = vn1;                          \
    } while (0)

    // ---- 32 rows, unrolled by 2 (XA/XB alternate; static indices only) ----
    #pragma unroll 1
    for (int i = 0; i < 32; i += 2) {
        {   // row i: consume XA, prefetch row i+1 into XB
            float hL0 = 0.f, hL1 = 0.f, vL0 = 0.f, vL1 = 0.f;
            #pragma unroll
            for (int j = 0; j < 32; ++j) {
                XB[j] = xp[(size_t)((i + 1) * 32 + j) * SB];   // i+1 <= 31
                CELL(i, j, XA[j]);
            }
        }
        {   // row i+1: consume XB, prefetch row i+2 into XA (if it exists)
            float hL0 = 0.f, hL1 = 0.f, vL0 = 0.f, vL1 = 0.f;
            if (i < 30) {
                #pragma unroll
                for (int j = 0; j < 32; ++j) {
                    XA[j] = xp[(size_t)((i + 2) * 32 + j) * SB];
                    CELL(i + 1, j, XB[j]);
                }
            } else {
                #pragma unroll
                for (int j = 0; j < 32; ++j) {
                    CELL(i + 1, j, XB[j]);
                }
            }
        }
    }
#undef CELL
}

extern "C" void kernel_launch(void* const* d_in, const int* in_sizes, int n_in,
                              void* d_out, int out_size, void* d_ws, size_t ws_size,
                              hipStream_t stream) {
    const float* x     = (const float*)d_in[0];
    const float* A1    = (const float*)d_in[1];
    const float* A2    = (const float*)d_in[2];
    const float* B1    = (const float*)d_in[3];
    const float* B2    = (const float*)d_in[4];
    const float* C1    = (const float*)d_in[5];
    const float* C2    = (const float*)d_in[6];
    const float* omega = (const float*)d_in[7];
    float* out = (float*)d_out;

    dim3 grid(256);                 // 16 b x 16 d-groups; 64 d-lanes each
    dim3 block(64);
    hipLaunchKernelGGL(ssm2d_kernel, grid, block, 0, stream,
                       x, A1, A2, B1, B2, C1, C2, omega, out);
}

// Round 23
// 51.581 us; speedup vs baseline: 1.4515x; 1.4515x over previous
//
#include <hip/hip_runtime.h>
#include <math.h>

// Sizes fixed by the reference.
#define BSZ  16
#define DIM  1024
#define SB   (BSZ * DIM)              // floats between consecutive s-cells
#define ROWSTRIDE ((size_t)32 * SB)   // floats between image rows (s += 32)

__device__ __forceinline__ float sigmoidf_(float v) {
    return __builtin_amdgcn_rcpf(1.0f + __expf(-v));
}

// R23 — HALO-SPLIT STREAMING. R22's streaming decomposition (lane=(b,d),
// s serial, register state, no LDS/barriers) had clean traffic but only
// 256 waves = 1 wave/CU (occupancy 2.7%) -> latency-starved, 74.9us.
// Fix: exploit contractivity. a1,a2 = sigmoid/2 < 0.5; worst-case per-row
// gain a1+a2 <~ 0.67 -> influence decays >= 0.67^dist. Truncate deps at
// >20 rows: split each image into 4 row-quarters computed independently.
//   quarter q: compute rows [max(0, 8q-20), 8q+8), output rows [8q, 8q+8)
//   q0,q1,q2 start at row 0 -> EXACT. Only q3 truncates (start row 4,
//   distance >= 21: err ~ 0.67^21 * 18 * 3 ~ 3e-3 << 0.27 threshold).
// Units: 256 -> 1024 waves = 4/CU (1/SIMD). Halo rows use a state-only
// cell (no y/silu/store). All 4 quarters of one (b,g) land on the same
// XCD (q not in the xcd bits) -> halo x-reads are L2-shared.
__global__ __launch_bounds__(64, 1) void ssm2d_kernel(
    const float* __restrict__ x,
    const float* __restrict__ A1, const float* __restrict__ A2,
    const float* __restrict__ B1, const float* __restrict__ B2,
    const float* __restrict__ C1, const float* __restrict__ C2,
    const float* __restrict__ omega,
    float* __restrict__ out)
{
    const int lx   = blockIdx.x;          // 0..1023
    const int xcd  = lx & 7;
    const int rest = lx >> 3;             // 0..127
    const int gg   = rest & 1;
    const int q    = (rest >> 1) & 3;     // row-quarter
    const int b    = rest >> 3;           // 0..15
    const int g    = xcd * 2 + gg;        // d-group 0..15 (64 d each)
    const int d    = g * 64 + threadIdx.x;

    // ---- per-lane coefficients ----
    const float2 fA1 = *reinterpret_cast<const float2*>(A1 + 2 * d);
    const float2 fA2 = *reinterpret_cast<const float2*>(A2 + 2 * d);
    const float2 fB1 = *reinterpret_cast<const float2*>(B1 + 2 * d);
    const float2 fB2 = *reinterpret_cast<const float2*>(B2 + 2 * d);
    const float2 fC1 = *reinterpret_cast<const float2*>(C1 + 2 * d);
    const float2 fC2 = *reinterpret_cast<const float2*>(C2 + 2 * d);
    const float  om  = omega[d];

    const float a1c0 = sigmoidf_(fA1.x) * 0.5f, a1c1 = sigmoidf_(fA1.y) * 0.5f;
    const float a2c0 = sigmoidf_(fA2.x) * 0.5f, a2c1 = sigmoidf_(fA2.y) * 0.5f;
    const float b1c0 = sigmoidf_(fB1.x) * 0.5f, b1c1 = sigmoidf_(fB1.y) * 0.5f;
    const float b2c0 = sigmoidf_(fB2.x) * 0.5f, b2c1 = sigmoidf_(fB2.y) * 0.5f;
    const float sc   = 0.70710678118654752f;
    const float c1s0 = fC1.x * sc, c1s1 = fC1.y * sc;
    const float c2s0 = fC2.x * sc, c2s1 = fC2.y * sc;

    const int out_start = q * 8;
    const int r_start   = (out_start > 20) ? (out_start - 20) : 0;

    const float* xrow = x   + (size_t)b * DIM + d + (size_t)r_start * ROWSTRIDE;
    float*       orow = out + (size_t)b * DIM + d + (size_t)out_start * ROWSTRIDE;

    // ---- prev-row state in registers (statically indexed) ----
    float H0[32], H1[32], V0[32], V1[32];
    #pragma unroll
    for (int j = 0; j < 32; ++j) { H0[j] = 0.f; H1[j] = 0.f; V0[j] = 0.f; V1[j] = 0.f; }

    // ---- row prefetch buffers ----
    float XA[32], XB[32];
    #pragma unroll
    for (int j = 0; j < 32; ++j) XA[j] = xrow[(size_t)j * SB];

    // ---- halo rows: state update only (no y/silu/store) ----
    #pragma unroll 1
    for (int r = r_start; r < out_start; ++r) {
        const float* xnext = xrow + ROWSTRIDE;   // r+1 <= out_start <= 24 < 32
        float hL0 = 0.f, hL1 = 0.f, vL0 = 0.f, vL1 = 0.f;
        #pragma unroll
        for (int j = 0; j < 32; ++j) {
            XB[j] = xnext[(size_t)j * SB];
            const float xv  = XA[j];
            const float vn0 = fmaf(a2c0, H0[j], fmaf(a1c0, V0[j], b2c0 * xv));
            const float vn1 = fmaf(a2c1, H1[j], fmaf(a1c1, V1[j], b2c1 * xv));
            const float hn0 = fmaf(a1c0, hL0, fmaf(a2c0, vL0, b1c0 * xv));
            const float hn1 = fmaf(a1c1, hL1, fmaf(a2c1, vL1, b1c1 * xv));
            H0[j] = hn0; H1[j] = hn1; V0[j] = vn0; V1[j] = vn1;
            hL0 = hn0; hL1 = hn1; vL0 = vn0; vL1 = vn1;
        }
        #pragma unroll
        for (int j = 0; j < 32; ++j) XA[j] = XB[j];
        xrow += ROWSTRIDE;
    }

    // ---- output rows: full cell + silu + store ----
    #pragma unroll 1
    for (int r = 0; r < 8; ++r) {
        const bool last = (out_start + r) == 31;
        const float* xnext = last ? xrow : (xrow + ROWSTRIDE);  // clamp OOB
        float hL0 = 0.f, hL1 = 0.f, vL0 = 0.f, vL1 = 0.f;
        #pragma unroll
        for (int j = 0; j < 32; ++j) {
            XB[j] = xnext[(size_t)j * SB];
            const float xv  = XA[j];
            const float vn0 = fmaf(a2c0, H0[j], fmaf(a1c0, V0[j], b2c0 * xv));
            const float vn1 = fmaf(a2c1, H1[j], fmaf(a1c1, V1[j], b2c1 * xv));
            const float hn0 = fmaf(a1c0, hL0, fmaf(a2c0, vL0, b1c0 * xv));
            const float hn1 = fmaf(a1c1, hL1, fmaf(a2c1, vL1, b1c1 * xv));
            float y = hn0 * c1s0;
            y = fmaf(hn1, c1s1, y);
            y = fmaf(vn0, c2s0, y);
            y = fmaf(vn1, c2s1, y);
            const float z = fmaf(xv, om, y);
            orow[(size_t)j * SB] = z * sigmoidf_(z);
            H0[j] = hn0; H1[j] = hn1; V0[j] = vn0; V1[j] = vn1;
            hL0 = hn0; hL1 = hn1; vL0 = vn0; vL1 = vn1;
        }
        #pragma unroll
        for (int j = 0; j < 32; ++j) XA[j] = XB[j];
        xrow += ROWSTRIDE;
        orow += ROWSTRIDE;
    }
}

extern "C" void kernel_launch(void* const* d_in, const int* in_sizes, int n_in,
                              void* d_out, int out_size, void* d_ws, size_t ws_size,
                              hipStream_t stream) {
    const float* x     = (const float*)d_in[0];
    const float* A1    = (const float*)d_in[1];
    const float* A2    = (const float*)d_in[2];
    const float* B1    = (const float*)d_in[3];
    const float* B2    = (const float*)d_in[4];
    const float* C1    = (const float*)d_in[5];
    const float* C2    = (const float*)d_in[6];
    const float* omega = (const float*)d_in[7];
    float* out = (float*)d_out;

    dim3 grid(1024);   // 16 b x 16 d-groups x 4 row-quarters
    dim3 block(64);
    hipLaunchKernelGGL(ssm2d_kernel, grid, block, 0, stream,
                       x, A1, A2, B1, B2, C1, C2, omega, out);
}

// Round 24
// 38.561 us; speedup vs baseline: 1.9416x; 1.3376x over previous
//
#include <hip/hip_runtime.h>
#include <math.h>

// Sizes fixed by the reference.
#define BSZ  16
#define DIM  1024
#define DPB  16        // d-channels per tile
#define THREADS 1024   // waves 0-7 compute, waves 8-15 memory
#define TPB  4         // tiles per block (b = 4*bq + k), grid = 256 = 1 block/CU
#define SSTRIDE 17     // LDS float-stride per s-cell: 17*31=527==15 (mod 32)
#define BUFF 17472     // floats per buffer (covers prefetch overrun)
#define LDSB (2 * BUFF * 4)   // 139776 B -> 1 block/CU

__device__ __forceinline__ float sigmoidf_(float v) {
    return __builtin_amdgcn_rcpf(1.0f + __expf(-v));
}

// Barrier without __syncthreads()'s implicit vmcnt(0) drain: only LDS
// visibility is needed across phases (global stores retire in background,
// prefetch-load consumption is ordered by the compiler's counted vmcnt).
__device__ __forceinline__ void soft_barrier() {
    asm volatile("s_waitcnt lgkmcnt(0)" ::: "memory");
    __builtin_amdgcn_s_barrier();
    asm volatile("" ::: "memory");
}

extern __shared__ float xs[];

// 2D SSM run as the recurrence directly on x (== causal conv with the impulse
// response == reference FFT path, by linearity/shift-invariance/causality).
//
// FINAL (R24 = R14, the session best at 38.49us):
//  - anti-diagonal wavefront compute (lane = row i, step ts, j = ts-i);
//    neighbor state folded into v_fmac_f32_dpp wave_shr:1 (lane0 zeroed by
//    bound_ctrl:0, half-wave row-0 zeroed via a1z/a2z coefficients).
//  - XCD-contiguity swizzle: XCD x hosts d-groups [8x, 8x+8) so the XCD's
//    32 CUs cover 512B-contiguous d-spans per (s,b) row (+10% vs none).
//  - producer/consumer wave split, R7 memory order (ISSUE -> DRAIN -> STAGE),
//    soft barriers, PRE/POST single-mask steps.
// Falsified alternatives (each within-probe): barrier-drain removal (null),
// channel-XOR (write inflation), NT stores (write inflation), 128B granule
// (serialization), 2-deep prefetch (spill or null), 2 blocks/CU (null),
// streaming lane-per-(b,d) (occupancy-starved), halo-split (imbalance).
// Pattern roofline: ~98MB TCC-boundary traffic at the ~2.8-3.4 TB/s this
// scatter pattern sustains -> ~35us floor; this kernel sits ~10% above it.
__global__ __launch_bounds__(THREADS, 1) void ssm2d_kernel(
    const float* __restrict__ x,
    const float* __restrict__ A1, const float* __restrict__ A2,
    const float* __restrict__ B1, const float* __restrict__ B2,
    const float* __restrict__ C1, const float* __restrict__ C2,
    const float* __restrict__ omega,
    float* __restrict__ out)
{
    // ---- XCD-contiguity swizzle: XCD = lx&7 hosts dgrps 8*(lx&7)+hi ----
    const int lx   = blockIdx.x;           // 0..255
    const int xcd  = lx & 7;
    const int hi   = (lx >> 3) & 7;
    const int bq   = lx >> 6;              // 0..3 -> tiles b = 4*bq + k
    const int dgrp = 8 * xcd + hi;         // 0..63
    const int d0   = dgrp * DPB;
    const int t    = threadIdx.x;

    const int lane = t & 63;
    const int wv   = t >> 6;               // wave 0..15
    const int i    = lane & 31;            // compute: row owned by this lane

    // ---- compute-wave coefficients (waves 0-7 only) ----
    float a1c0, a1c1, a2c0, a2c1, b1c0, b1c1, b2c0, b2c1;
    float c1s0, c1s1, c2s0, c2s1, om;
    float a1z0, a1z1, a2z0, a2z1;
    int dd = 0;
    if (t < 512) {
        dd = 2 * wv + (lane >> 5);         // image (d-index) 0..15
        const int d = d0 + dd;
        const float2 fA1 = *reinterpret_cast<const float2*>(A1 + 2 * d);
        const float2 fA2 = *reinterpret_cast<const float2*>(A2 + 2 * d);
        const float2 fB1 = *reinterpret_cast<const float2*>(B1 + 2 * d);
        const float2 fB2 = *reinterpret_cast<const float2*>(B2 + 2 * d);
        const float2 fC1 = *reinterpret_cast<const float2*>(C1 + 2 * d);
        const float2 fC2 = *reinterpret_cast<const float2*>(C2 + 2 * d);
        om   = omega[d];
        a1c0 = sigmoidf_(fA1.x) * 0.5f;  a1c1 = sigmoidf_(fA1.y) * 0.5f;
        a2c0 = sigmoidf_(fA2.x) * 0.5f;  a2c1 = sigmoidf_(fA2.y) * 0.5f;
        b1c0 = sigmoidf_(fB1.x) * 0.5f;  b1c1 = sigmoidf_(fB1.y) * 0.5f;
        b2c0 = sigmoidf_(fB2.x) * 0.5f;  b2c1 = sigmoidf_(fB2.y) * 0.5f;
        const float sc = 0.70710678118654752f;
        c1s0 = fC1.x * sc;  c1s1 = fC1.y * sc;
        c2s0 = fC2.x * sc;  c2s1 = fC2.y * sc;
        a1z0 = (i == 0) ? 0.f : a1c0;  a1z1 = (i == 0) ? 0.f : a1c1;
        a2z0 = (i == 0) ? 0.f : a2c0;  a2z1 = (i == 0) ? 0.f : a2c1;
    }

    // ---- memory-wave mappings & load set ----
    const int m    = t & 511;
    const int srow = m >> 2;               // 0..127
    const int qq   = (m & 3) * 4;
    const size_t gb = (size_t)srow * (BSZ * DIM) + d0 + qq;
    float4 L[8];

#define ISSUE(TILE) do {                                                     \
        const float* gp = x + gb + (size_t)(TILE) * DIM;                     \
        _Pragma("unroll") for (int k2 = 0; k2 < 8; ++k2)                     \
            L[k2] = *reinterpret_cast<const float4*>(                        \
                gp + (size_t)k2 * (128 * BSZ * DIM));                        \
    } while (0)

#define STAGEFROM(BUFO) do {                                                 \
        _Pragma("unroll") for (int k2 = 0; k2 < 8; ++k2) {                   \
            float* p = (BUFO) + SSTRIDE * (srow + 128 * k2) + qq;            \
            p[0] = L[k2].x; p[1] = L[k2].y;                                  \
            p[2] = L[k2].z; p[3] = L[k2].w; }                                \
    } while (0)

#define DRAINTO(TILE, BUFO) do {                                             \
        float* op = out + gb + (size_t)(TILE) * DIM;                         \
        _Pragma("unroll") for (int k2 = 0; k2 < 8; ++k2) {                   \
            const float* p = (BUFO) + SSTRIDE * (srow + 128 * k2) + qq;      \
            float4 v; v.x = p[0]; v.y = p[1]; v.z = p[2]; v.w = p[3];        \
            *reinterpret_cast<float4*>(                                      \
                op + (size_t)k2 * (128 * BSZ * DIM)) = v; }                  \
    } while (0)

    // ---- prologue: all 1024 threads stage tile 0 into buf0 ----
    {
        const int srow4 = t >> 2;          // 0..255
        const int qq4   = (t & 3) * 4;
        const float* gp0 = x + (size_t)srow4 * (BSZ * DIM)
                             + (size_t)(4 * bq) * DIM + d0 + qq4;
        float4 P[4];
        #pragma unroll
        for (int k2 = 0; k2 < 4; ++k2)
            P[k2] = *reinterpret_cast<const float4*>(
                gp0 + (size_t)k2 * (256 * BSZ * DIM));
        #pragma unroll
        for (int k2 = 0; k2 < 4; ++k2) {
            float* p = xs + SSTRIDE * (srow4 + 256 * k2) + qq4;
            p[0] = P[k2].x; p[1] = P[k2].y; p[2] = P[k2].z; p[3] = P[k2].w;
        }
    }
    soft_barrier();

    // ---- compute step macros ----
#define SBODY(XV_EXPR)                                                       \
        const float xv = (XV_EXPR);                                          \
        const float t10 = b1c0 * xv, t11 = b1c1 * xv;                        \
        const float hn0 = fmaf(a1c0, h0, fmaf(a2c0, v0, t10));               \
        const float hn1 = fmaf(a1c1, h1, fmaf(a2c1, v1, t11));               \
        float vn0 = b2c0 * xv, vn1 = b2c1 * xv;                              \
        asm("s_nop 1\n\t"                                                    \
            "v_fmac_f32_dpp %0, %2, %6 wave_shr:1 row_mask:0xf bank_mask:0xf bound_ctrl:0\n\t" \
            "v_fmac_f32_dpp %1, %3, %7 wave_shr:1 row_mask:0xf bank_mask:0xf bound_ctrl:0\n\t" \
            "v_fmac_f32_dpp %0, %4, %8 wave_shr:1 row_mask:0xf bank_mask:0xf bound_ctrl:0\n\t" \
            "v_fmac_f32_dpp %1, %5, %9 wave_shr:1 row_mask:0xf bank_mask:0xf bound_ctrl:0"     \
            : "+v"(vn0), "+v"(vn1)                                           \
            : "v"(h0), "v"(h1), "v"(v0), "v"(v1),                            \
              "v"(a2z0), "v"(a2z1), "v"(a1z0), "v"(a1z1));                   \
        float y = hn0 * c1s0;                                                \
        y = fmaf(hn1, c1s1, y);                                              \
        y = fmaf(vn0, c2s0, y);                                              \
        y = fmaf(vn1, c2s1, y);                                              \
        const float z = fmaf(xv, om, y);                                     \
        const float o = z * sigmoidf_(z);

#define SSTEP_PRE(TS, XQ) do {                                               \
        const bool val = (i <= (TS));                                        \
        SBODY(val ? (XQ) : 0.f)                                              \
        if (val) rp[SSTRIDE * (TS)] = o;                                     \
        h0 = hn0; h1 = hn1; v0 = vn0; v1 = vn1; } while (0)

#define SSTEP_POST(TS, XQ) do { SBODY(XQ)                                    \
        if (i >= (TS) - 31) rp[SSTRIDE * (TS)] = o;                          \
        h0 = hn0; h1 = hn1; v0 = vn0; v1 = vn1; } while (0)

    // ---- main loop: one soft barrier per tile ----
    #pragma unroll 1
    for (int k = 0; k < TPB; ++k) {
        if (t < 512) {
            // -------- compute waves --------
            float* rp = xs + (k & 1) * BUFF + 527 * i + dd;
            float h0 = 0.f, h1 = 0.f, v0 = 0.f, v1 = 0.f;
            float xq0 = rp[0 * SSTRIDE];
            float xq1 = rp[1 * SSTRIDE];
            float xq2 = rp[2 * SSTRIDE];
            #pragma unroll
            for (int ts = 0; ts < 30; ts += 3) {
                SSTEP_PRE(ts + 0, xq0); xq0 = rp[SSTRIDE * (ts + 3)];
                SSTEP_PRE(ts + 1, xq1); xq1 = rp[SSTRIDE * (ts + 4)];
                SSTEP_PRE(ts + 2, xq2); xq2 = rp[SSTRIDE * (ts + 5)];
            }
            SSTEP_PRE(30, xq0); xq0 = rp[SSTRIDE * 33];
            #pragma unroll
            for (int ts = 31; ts < 61; ts += 3) {
                SSTEP_POST(ts + 0, xq1); xq1 = rp[SSTRIDE * (ts + 3)];
                SSTEP_POST(ts + 1, xq2); xq2 = rp[SSTRIDE * (ts + 4)];
                SSTEP_POST(ts + 2, xq0); xq0 = rp[SSTRIDE * (ts + 5)];
            }
            SSTEP_POST(61, xq1);
            SSTEP_POST(62, xq2);
        } else {
            // -------- memory waves (R7 order: issue, drain, stage) --------
            float* bufO = xs + ((k + 1) & 1) * BUFF;
            if (k < TPB - 1) ISSUE(4 * bq + k + 1);      // head start
            if (k >= 1) DRAINTO(4 * bq + k - 1, bufO);   // read bufO first
            if (k < TPB - 1) STAGEFROM(bufO);            // consume same-phase L
        }
        soft_barrier();
    }

    // ---- epilogue: all 1024 threads drain tile 3 from buf1 ----
    {
        const int srow4 = t >> 2;
        const int qq4   = (t & 3) * 4;
        const float* bufE = xs + ((TPB - 1) & 1) * BUFF;
        float* op = out + (size_t)srow4 * (BSZ * DIM)
                        + (size_t)(4 * bq + TPB - 1) * DIM + d0 + qq4;
        #pragma unroll
        for (int k2 = 0; k2 < 4; ++k2) {
            const float* p = bufE + SSTRIDE * (srow4 + 256 * k2) + qq4;
            float4 v; v.x = p[0]; v.y = p[1]; v.z = p[2]; v.w = p[3];
            *reinterpret_cast<float4*>(op + (size_t)k2 * (256 * BSZ * DIM)) = v;
        }
    }
}

extern "C" void kernel_launch(void* const* d_in, const int* in_sizes, int n_in,
                              void* d_out, int out_size, void* d_ws, size_t ws_size,
                              hipStream_t stream) {
    const float* x     = (const float*)d_in[0];
    const float* A1    = (const float*)d_in[1];
    const float* A2    = (const float*)d_in[2];
    const float* B1    = (const float*)d_in[3];
    const float* B2    = (const float*)d_in[4];
    const float* C1    = (const float*)d_in[5];
    const float* C2    = (const float*)d_in[6];
    const float* omega = (const float*)d_in[7];
    float* out = (float*)d_out;

    (void)hipFuncSetAttribute(reinterpret_cast<const void*>(ssm2d_kernel),
                              hipFuncAttributeMaxDynamicSharedMemorySize, LDSB);

    dim3 grid(256);                 // 64 d-groups x 4 b-quads; 4 tiles/block
    dim3 block(THREADS);
    hipLaunchKernelGGL(ssm2d_kernel, grid, block, LDSB, stream,
                       x, A1, A2, B1, B2, C1, C2, omega, out);
}